// Round 17
// baseline (135.997 us; speedup 1.0000x reference)
//
#include <hip/hip_runtime.h>
#include <math.h>

#define NQ    8192     // N queries per batch
#define NP    8192     // M points per batch
#define NF    128      // feature dim
#define NOUT  512      // output dim
#define NB    2        // batches
#define KNN   10
#define BNQ   (NB*NQ)  // 16384 total queries
#define CELLS 4096     // 16^3 grid

typedef unsigned long long u64;
typedef unsigned int u32;
typedef unsigned short ushort_t;
typedef __attribute__((ext_vector_type(8))) short bf16x8;
typedef __attribute__((ext_vector_type(4))) float f32x4;

// Normal quantile edges Phi^-1(i/16); cell c covers (E[c], E[c+1]].
__device__ const float EDGEX[17] = {
  -1e30f, -1.53412f, -1.15035f, -0.88715f, -0.67449f, -0.48878f, -0.31864f,
  -0.15731f, 0.0f, 0.15731f, 0.31864f, 0.48878f, 0.67449f, 0.88715f,
  1.15035f, 1.53412f, 1e30f };

__device__ __forceinline__ int bucket(float v) {
  int c = 0;
  c += (v > -1.53412f); c += (v > -1.15035f); c += (v > -0.88715f);
  c += (v > -0.67449f); c += (v > -0.48878f); c += (v > -0.31864f);
  c += (v > -0.15731f); c += (v > 0.0f);      c += (v > 0.15731f);
  c += (v > 0.31864f);  c += (v > 0.48878f);  c += (v > 0.67449f);
  c += (v > 0.88715f);  c += (v > 1.15035f);  c += (v > 1.53412f);
  return c;          // 0..15
}

__device__ __forceinline__ u64 shfl64(u64 v, int src) {
  unsigned lo = (unsigned)__shfl((int)(unsigned)(v & 0xffffffffull), src, 64);
  unsigned hi = (unsigned)__shfl((int)(unsigned)(v >> 32), src, 64);
  return ((u64)hi << 32) | lo;
}
__device__ __forceinline__ u64 shflup64(u64 v) {
  unsigned lo = (unsigned)__shfl_up((int)(unsigned)(v & 0xffffffffull), 1, 64);
  unsigned hi = (unsigned)__shfl_up((int)(unsigned)(v >> 32), 1, 64);
  return ((u64)hi << 32) | lo;
}

// Monotone f32->u32 bit map: mono(a) < mono(b) (unsigned) <=> a < b (float).
__device__ __forceinline__ unsigned fmono(float f) {
  unsigned u = __float_as_uint(f);
  return u ^ ((unsigned)((int)u >> 31) | 0x80000000u);
}
// nextafter(f, +inf) for finite f; +INF/NaN -> NaN (harmless in fminf).
__device__ __forceinline__ float nextupf(float f) {
  unsigned u = __float_as_uint(f);
  unsigned n = (u & 0x80000000u) ? ((u == 0x80000000u) ? 1u : u - 1u) : u + 1u;
  return __uint_as_float(n);
}

__device__ __forceinline__ float wmin64f(float v) {
#pragma unroll
  for (int off = 1; off < 64; off <<= 1)
    v = fminf(v, __shfl_xor(v, off, 64));
  return v;   // broadcast min across all 64 lanes (r5-verified)
}

// r8-verified order-independent distributed insert (full-exec only).
__device__ __forceinline__ void insert_loop(float d2, int idxv, int lane,
                                            u64& lst, float& dlv, float& th) {
  for (;;) {
    u64 mask = __ballot(d2 < th);
    if (!mask) break;
    int src = __builtin_ctzll(mask);
    float cd = __uint_as_float(
        (unsigned)__builtin_amdgcn_readlane(__float_as_int(d2), src));
    int  ci = __builtin_amdgcn_readlane(idxv, src);
    u64 kk = ((u64)fmono(cd) << 32) | (u32)ci;
    u64   prev  = shflup64(lst);
    float prevd = __shfl(dlv, lane - 1, 64);
    bool mylt = lst < kk;
    bool pins = (lane == 0) || (prev < kk);
    lst = mylt ? lst : (pins ? kk : prev);
    dlv = mylt ? dlv : (pins ? cd : prevd);
    float d9 = __uint_as_float(
        (unsigned)__builtin_amdgcn_readlane(__float_as_int(dlv), 9));
    th = fminf(th, nextupf(d9));
    if (lane == src) d2 = __builtin_nanf("");
  }
}

// round-to-nearest-even f32 -> bf16
__device__ __forceinline__ ushort_t f2bf(float x) {
  unsigned u = __float_as_uint(x);
  return (ushort_t)((u + 0x7FFFu + ((u >> 16) & 1u)) >> 16);
}

// ---------------------------------------------------------------------------
// Prep: W -> bf16 Wb; zero BOTH histograms (points + queries, contiguous).
// ---------------------------------------------------------------------------
__global__ __launch_bounds__(256) void prep_kernel(
    const float* __restrict__ W, ushort_t* __restrict__ Wb,
    int* __restrict__ histall)
{
  const int tid = blockIdx.x * 256 + threadIdx.x;
  Wb[tid] = f2bf(W[tid]);
  if (tid < 2 * NB * CELLS) histall[tid] = 0;
}

// ---------------------------------------------------------------------------
// Histogram points (tid<16384) and queries (tid>=16384) per cell.
// ---------------------------------------------------------------------------
__global__ __launch_bounds__(256) void hist2_kernel(
    const float* __restrict__ gpcd, const float* __restrict__ geometry,
    int* __restrict__ hist, int* __restrict__ qhist)
{
  const int tid = blockIdx.x * 256 + threadIdx.x;   // 0..32767
  if (tid < NB * NP) {
    const float* p = gpcd + (size_t)tid * 3;
    const int cell = (bucket(p[0]) << 8) | (bucket(p[1]) << 4) | bucket(p[2]);
    atomicAdd(&hist[(tid >> 13) * CELLS + cell], 1);
  } else {
    const int qt = tid - NB * NP;
    const float* g = geometry + (size_t)qt * 3;
    const int cell = (bucket(g[0]) << 8) | (bucket(g[1]) << 4) | bucket(g[2]);
    atomicAdd(&qhist[(qt >> 13) * CELLS + cell], 1);
  }
}

// ---------------------------------------------------------------------------
// Exclusive scan (segmented at batch boundary). Block 0: point hist ->
// cellstart+cursor. Block 1: query hist -> qcursor only.  (r12-verified scan)
// ---------------------------------------------------------------------------
__global__ __launch_bounds__(1024) void scan2_kernel(
    const int* __restrict__ hist, const int* __restrict__ qhist,
    int* __restrict__ cellstart, int* __restrict__ cursor,
    int* __restrict__ qcursor)
{
  __shared__ int tot[1024];
  const int t = threadIdx.x;
  const bool isQ = blockIdx.x != 0;
  const int* __restrict__ src = isQ ? qhist : hist;
  int v[8]; int s = 0;
#pragma unroll
  for (int i = 0; i < 8; ++i) { v[i] = src[t * 8 + i]; s += v[i]; }
  tot[t] = s;
  __syncthreads();
  int x = s;
  for (int off = 1; off < 1024; off <<= 1) {
    int y = 0;
    if (t >= off && ((t >= 512) == ((t - off) >= 512))) y = tot[t - off];
    __syncthreads();
    x += y; tot[t] = x;
    __syncthreads();
  }
  int run = x - s;
#pragma unroll
  for (int i = 0; i < 8; ++i) {
    const int cf = t * 8 + i;
    const int b = cf >> 12, c = cf & (CELLS - 1);
    if (isQ) {
      qcursor[cf] = run;
    } else {
      cellstart[b * (CELLS + 1) + c] = run;
      cursor[cf] = run;
    }
    run += v[i];
  }
  if (!isQ && t == 0) {
    cellstart[CELLS] = NP;
    cellstart[(CELLS + 1) + CELLS] = NP;
  }
}

// ---------------------------------------------------------------------------
// Scatter points into cell-sorted order (r12-verified) and queries into
// cell-sorted order as float4(x,y,z, asfloat(orig local index)).
// ---------------------------------------------------------------------------
__global__ __launch_bounds__(256) void scatter2_kernel(
    const float* __restrict__ gpcd, const float* __restrict__ geometry,
    int* __restrict__ cursor, int* __restrict__ qcursor,
    float4* __restrict__ sortedPts, int* __restrict__ sortedIdx,
    float4* __restrict__ sortedQ)
{
  const int tid = blockIdx.x * 256 + threadIdx.x;   // 0..32767
  if (tid < NB * NP) {
    const int b = tid >> 13, m = tid & 8191;
    const float* p = gpcd + (size_t)tid * 3;
    const float x = p[0], y = p[1], z = p[2];
    const int cell = (bucket(x) << 8) | (bucket(y) << 4) | bucket(z);
    const int pos = atomicAdd(&cursor[b * CELLS + cell], 1);
    sortedPts[(b << 13) + pos] = make_float4(x, y, z, x * x + y * y + z * z);
    sortedIdx[(b << 13) + pos] = m;
  } else {
    const int qt = tid - NB * NP;
    const int b = qt >> 13, m = qt & 8191;
    const float* g = geometry + (size_t)qt * 3;
    const float x = g[0], y = g[1], z = g[2];
    const int cell = (bucket(x) << 8) | (bucket(y) << 4) | bucket(z);
    const int pos = atomicAdd(&qcursor[b * CELLS + cell], 1);
    sortedQ[(b << 13) + pos] = make_float4(x, y, z, __int_as_float(m));
  }
}

// ---------------------------------------------------------------------------
// Exact kNN + interp, ONE WAVE PER QUERY (r16-verified body). Waves now
// process CELL-SORTED queries: the 4 waves of a block sit in adjacent cells,
// so shell counts (and thus wave lifetimes) are uniform within a block and
// neighboring waves hit the same candidate segments in L1/L2. Output is
// written to the query's original slot (exact per-query results are
// order-independent, so the nondeterministic scatter order is harmless).
// ---------------------------------------------------------------------------
__global__ __launch_bounds__(256) void knn_interp_grid(
    const float4* __restrict__ sortedQ,
    const float4* __restrict__ sortedPts, const int* __restrict__ sortedIdx,
    const int* __restrict__ cellstart, const float* __restrict__ features,
    ushort_t* __restrict__ Abf)
{
  const int lane = threadIdx.x & 63;
  const int qs   = (blockIdx.x << 2) | (threadIdx.x >> 6);  // sorted slot
  const int b    = qs >> 13;

  const float4 sq = sortedQ[qs];
  const float qx = sq.x, qy = sq.y, qz = sq.z;
  const int morig = __float_as_int(sq.w);       // original local query index
  const float q2 = qx * qx + qy * qy + qz * qz;
  const float c2x = -2.f * qx, c2y = -2.f * qy, c2z = -2.f * qz;
  const int cx = bucket(qx), cy = bucket(qy), cz = bucket(qz);

  const float4* __restrict__ SP = sortedPts + ((size_t)b << 13);
  const int*    __restrict__ SI = sortedIdx + ((size_t)b << 13);
  const int*    __restrict__ CS = cellstart + b * (CELLS + 1);

  u64   list = ~0ull;
  float dl   = INFINITY;
  float th   = INFINITY;
  bool  firstbatch = true;

  for (int s = 1; s <= 15; ++s) {
    const int w20 = 2 * s - 1;
    const u32 Mw  = (0x100000u + (u32)w20 - 1) / (u32)w20;   // ceil(2^20/w)
    const int Scap = 8 * s + 2 * w20 * w20;
    const int S = Scap + (s == 1 ? 1 : 0);
    for (int segbase = 0; segbase < S; segbase += 64) {
      const int k = segbase + lane;
      int st = 0, len = 0;
      if (k < S) {
        int x, y, zlo, zhi; bool valid;
        if (k < 8 * s) {
          const int twos = 2 * s;
          int side = 0, t = k;
          if (t >= twos) { ++side; t -= twos; }
          if (t >= twos) { ++side; t -= twos; }
          if (t >= twos) { ++side; t -= twos; }
          int dx, dy;
          if      (side == 0) { dx = -s + t; dy = -s; }
          else if (side == 1) { dx = s;      dy = -s + t; }
          else if (side == 2) { dx = s - t;  dy = s; }
          else                { dx = -s;     dy = s - t; }
          x = cx + dx; y = cy + dy;
          zlo = max(cz - s, 0); zhi = min(cz + s, 15);
          valid = (x >= 0) & (x < 16) & (y >= 0) & (y < 16);
        } else if (k < Scap) {
          const int kp = k - 8 * s;
          const u32 jj = (u32)(kp >> 1);
          const int z  = (kp & 1) ? (cz + s) : (cz - s);
          const u32 qd = (jj * Mw) >> 20;          // jj / w (exact, jj<841)
          const u32 rm = jj - qd * (u32)w20;       // jj % w
          x = cx - (s - 1) + (int)rm;
          y = cy - (s - 1) + (int)qd;
          zlo = zhi = z;
          valid = (x >= 0) & (x < 16) & (y >= 0) & (y < 16) & (z >= 0) & (z < 16);
        } else {                                   // center cell (s==1 only)
          x = cx; y = cy; zlo = zhi = cz; valid = true;
        }
        if (valid) {
          const int base = ((x << 4) | y) << 4;
          st  = CS[base + zlo];
          len = CS[base + zhi + 1] - st;
        }
      }
      // exclusive prefix of len across the wave (full-exec shuffles)
      int pre = len;
#pragma unroll
      for (int off = 1; off < 64; off <<= 1) {
        int t2 = __shfl_up(pre, off, 64);
        if (lane >= off) pre += t2;
      }
      const int total = __shfl(pre, 63, 64);
      pre -= len;
      // consume candidates in 64-wide batches; ALL shuffles full-exec (r14 fix)
      for (int cb = 0; cb < total; cb += 64) {
        const int j  = cb + lane;
        const int jc = min(j, total - 1);
        int r = 0;
#pragma unroll
        for (int off = 32; off; off >>= 1) {
          const int c = r + off;
          const int pc = __shfl(pre, c & 63, 64);
          if (c < 64 && pc <= jc) r = c;
        }
        const int o = __shfl(st, r, 64) + (jc - __shfl(pre, r, 64));
        const float4 p = SP[o];
        const int   idv = SI[o];
        float d2 = fmaf(c2x, p.x, fmaf(c2y, p.y, fmaf(c2z, p.z, q2 + p.w)));
        d2 = fmaxf(d2, 0.f);
        if (j >= total) d2 = __builtin_nanf("");   // mask AFTER the load

        if (firstbatch) {
          // r5-verified tau-knockout: tau = 10th-smallest batch candidate
          float lm = d2;
          float tau = INFINITY;
#pragma unroll
          for (int r2 = 0; r2 < KNN; ++r2) {
            tau = wmin64f(lm);
            u64 mk = __ballot(lm == tau);
            int w2 = __builtin_ctzll(mk);
            if (lane == w2) lm = INFINITY;
          }
          th = fminf(th, nextupf(tau));   // admit ties at tau; exact via keys
          firstbatch = false;
        }
        insert_loop(d2, idv, lane, list, dl, th);
      }
    }
    // ---- certification (wave-uniform branch) ----
    const float d2_10 = __uint_as_float(
        (unsigned)__builtin_amdgcn_readlane(__float_as_int(dl), 9));
    float m = fminf(qx - EDGEX[max(cx - s, 0)], EDGEX[min(cx + s + 1, 16)] - qx);
    m = fminf(m, fminf(qy - EDGEX[max(cy - s, 0)], EDGEX[min(cy + s + 1, 16)] - qy));
    m = fminf(m, fminf(qz - EDGEX[max(cz - s, 0)], EDGEX[min(cz + s + 1, 16)] - qz));
    if (d2_10 <= m * m) break;          // INF/NaN compares false -> expand
  }

  // ---- weights + feature interpolation (r9/r10-verified tail) ----
  const float* __restrict__ F = features + (size_t)b * NP * NF;
  float w = 1.0f / (sqrtf(dl) + 1e-8f);          // meaningful on lanes 0..9
  float wsum = 0.0f;
#pragma unroll
  for (int jj = 0; jj < KNN; ++jj) wsum += __shfl(w, jj, 64);

  float a0 = 0.0f, a1 = 0.0f;
#pragma unroll
  for (int jj = 0; jj < KNN; ++jj) {
    float wj = __shfl(w, jj, 64) / wsum;
    int  mi  = (int)(u32)(shfl64(list, jj) & 0xffffffffull);
    const float2 f2 = *(const float2*)(F + (size_t)mi * NF + (lane << 1));
    a0 = fmaf(wj, f2.x, a0);
    a1 = fmaf(wj, f2.y, a1);
  }
  unsigned pack = (unsigned)f2bf(a0) | ((unsigned)f2bf(a1) << 16);
  *(unsigned*)(Abf + (size_t)((b << 13) + morig) * NF + (lane << 1)) = pack;
}

// ---------------------------------------------------------------------------
// Stage C (MFMA, r9/r10-verified): out[q][o] = sum_f A[q][f]*Wb[o][f]+bias[o]
// ---------------------------------------------------------------------------
__global__ __launch_bounds__(256) void proj_mfma(
    const ushort_t* __restrict__ Abf, const ushort_t* __restrict__ Wb,
    const float* __restrict__ bias, float* __restrict__ out)
{
  const int lane = threadIdx.x & 63;
  const int w    = threadIdx.x >> 6;
  const int mt   = blockIdx.x & 127;
  const int ot   = blockIdx.x >> 7;
  const int m0   = (mt << 7) + ((w & 1) << 6);
  const int o0   = (ot << 6) + ((w >> 1) << 5);
  const int r    = lane & 15;
  const int kg   = (lane >> 4) << 3;

  f32x4 acc[4][2];
#pragma unroll
  for (int i = 0; i < 4; ++i)
#pragma unroll
    for (int jn = 0; jn < 2; ++jn) acc[i][jn] = (f32x4)0.0f;

#pragma unroll
  for (int ks = 0; ks < 4; ++ks) {
    const int k0 = (ks << 5) + kg;
    bf16x8 a[4], bb[2];
#pragma unroll
    for (int i = 0; i < 4; ++i)
      a[i] = *(const bf16x8*)(Abf + (size_t)(m0 + (i << 4) + r) * NF + k0);
#pragma unroll
    for (int jn = 0; jn < 2; ++jn)
      bb[jn] = *(const bf16x8*)(Wb + (size_t)(o0 + (jn << 4) + r) * NF + k0);
#pragma unroll
    for (int i = 0; i < 4; ++i)
#pragma unroll
      for (int jn = 0; jn < 2; ++jn)
        acc[i][jn] = __builtin_amdgcn_mfma_f32_16x16x32_bf16(
            a[i], bb[jn], acc[i][jn], 0, 0, 0);
  }

  const int crow = (lane >> 4) << 2;
#pragma unroll
  for (int jn = 0; jn < 2; ++jn) {
    const int oc = o0 + (jn << 4) + r;
    const float bv = bias[oc];
#pragma unroll
    for (int i = 0; i < 4; ++i) {
#pragma unroll
      for (int reg = 0; reg < 4; ++reg) {
        const int qm = m0 + (i << 4) + crow + reg;
        out[(size_t)qm * NOUT + oc] = acc[i][jn][reg] + bv;
      }
    }
  }
}

// ---------------------------------------------------------------------------
extern "C" void kernel_launch(void* const* d_in, const int* in_sizes, int n_in,
                              void* d_out, int out_size, void* d_ws, size_t ws_size,
                              hipStream_t stream) {
  const float* geometry = (const float*)d_in[0];   // [2,8192,3]
  const float* gpcd     = (const float*)d_in[1];   // [2,8192,3]
  const float* features = (const float*)d_in[2];   // [2,8192,128]
  const float* W        = (const float*)d_in[3];   // [512,128]
  const float* bias     = (const float*)d_in[4];   // [512]
  float* out = (float*)d_out;

  char* ws = (char*)d_ws;
  size_t off = 0;
  ushort_t* Abf  = (ushort_t*)(ws + off); off += (size_t)BNQ * NF * 2;   // 4 MiB
  float4* sortedPts = (float4*)(ws + off); off += (size_t)NB * NP * 16;  // 256 KiB
  float4* sortedQ   = (float4*)(ws + off); off += (size_t)BNQ * 16;      // 256 KiB
  ushort_t* Wb   = (ushort_t*)(ws + off); off += (size_t)NOUT * NF * 2;  // 128 KiB
  int* histall   = (int*)(ws + off); off += (size_t)2 * NB * CELLS * 4;  // 64 KiB
  int* hist      = histall;
  int* qhist     = histall + NB * CELLS;
  int* cellstart = (int*)(ws + off); off += (size_t)NB * (CELLS + 1) * 4 + 8;
  int* cursor    = (int*)(ws + off); off += (size_t)NB * CELLS * 4;
  int* qcursor   = (int*)(ws + off); off += (size_t)NB * CELLS * 4;
  int* sortedIdx = (int*)(ws + off); off += (size_t)NB * NP * 4;

  prep_kernel<<<256, 256, 0, stream>>>(W, Wb, histall);
  hist2_kernel<<<128, 256, 0, stream>>>(gpcd, geometry, hist, qhist);
  scan2_kernel<<<2, 1024, 0, stream>>>(hist, qhist, cellstart, cursor, qcursor);
  scatter2_kernel<<<128, 256, 0, stream>>>(gpcd, geometry, cursor, qcursor,
                                           sortedPts, sortedIdx, sortedQ);
  knn_interp_grid<<<BNQ / 4, 256, 0, stream>>>(sortedQ, sortedPts, sortedIdx,
                                               cellstart, features, Abf);
  proj_mfma<<<(BNQ / 128) * (NOUT / 64), 256, 0, stream>>>(Abf, Wb, bias, out);
}

// Round 18
// 107.665 us; speedup vs baseline: 1.2632x; 1.2632x over previous
//
#include <hip/hip_runtime.h>
#include <math.h>

#define NQ   8192      // N queries per batch
#define NP   8192      // M points per batch
#define NF   128       // feature dim
#define NOUT 512       // output dim
#define NB   2         // batches
#define KNN  10
#define BNQ  (NB*NQ)   // 16384 total queries
#define QW   2         // queries per wave
#define CAP  64        // candidate buffer slots per query

typedef unsigned long long u64;
typedef unsigned int u32;
typedef unsigned short ushort_t;
typedef __attribute__((ext_vector_type(8))) short bf16x8;
typedef __attribute__((ext_vector_type(4))) float f32x4;

__device__ __forceinline__ u64 shfl64(u64 v, int src) {
  unsigned lo = (unsigned)__shfl((int)(unsigned)(v & 0xffffffffull), src, 64);
  unsigned hi = (unsigned)__shfl((int)(unsigned)(v >> 32), src, 64);
  return ((u64)hi << 32) | lo;
}
__device__ __forceinline__ u64 shflup64(u64 v) {
  unsigned lo = (unsigned)__shfl_up((int)(unsigned)(v & 0xffffffffull), 1, 64);
  unsigned hi = (unsigned)__shfl_up((int)(unsigned)(v >> 32), 1, 64);
  return ((u64)hi << 32) | lo;
}

// Shifted distance for SELECTION: d2' = p2 - 2 q.p  (3 fma). True d2 = d2'+q2.
__device__ __forceinline__ float dist2s(float m2x, float m2y, float m2z,
                                        float4 p) {
  return fmaf(m2x, p.x, fmaf(m2y, p.y, fmaf(m2z, p.z, p.w)));
}

// Monotone f32->u32 bit map: mono(a) < mono(b) (unsigned) <=> a < b (float).
__device__ __forceinline__ unsigned fmono(float f) {
  unsigned u = __float_as_uint(f);
  return u ^ ((unsigned)((int)u >> 31) | 0x80000000u);
}
// nextafter(f, +inf) for finite f incl. negatives and -0 (r7-verified).
__device__ __forceinline__ float nextupf(float f) {
  unsigned u = __float_as_uint(f);
  unsigned n = (u & 0x80000000u) ? ((u == 0x80000000u) ? 1u : u - 1u) : u + 1u;
  return __uint_as_float(n);
}

__device__ __forceinline__ float wmin64f(float v) {
#pragma unroll
  for (int off = 1; off < 64; off <<= 1)
    v = fminf(v, __shfl_xor(v, off, 64));
  return v;   // broadcast min across all 64 lanes (r5-verified)
}

// r8-verified order-independent distributed insert (full-exec only).
__device__ __forceinline__ void insert_loop(float d2, int idxv, int lane,
                                            u64& lst, float& dlv, float& th) {
  for (;;) {
    u64 mask = __ballot(d2 < th);
    if (!mask) break;
    int src = __builtin_ctzll(mask);
    float cd = __uint_as_float(
        (unsigned)__builtin_amdgcn_readlane(__float_as_int(d2), src));
    int  ci = __builtin_amdgcn_readlane(idxv, src);
    u64 kk = ((u64)fmono(cd) << 32) | (u32)ci;
    u64   prev  = shflup64(lst);
    float prevd = __shfl(dlv, lane - 1, 64);
    bool mylt = lst < kk;
    bool pins = (lane == 0) || (prev < kk);
    lst = mylt ? lst : (pins ? kk : prev);
    dlv = mylt ? dlv : (pins ? cd : prevd);
    float d9 = __uint_as_float(
        (unsigned)__builtin_amdgcn_readlane(__float_as_int(dlv), 9));
    th = fminf(th, nextupf(d9));
    if (lane == src) d2 = __builtin_nanf("");
  }
}

// round-to-nearest-even f32 -> bf16
__device__ __forceinline__ ushort_t f2bf(float x) {
  unsigned u = __float_as_uint(x);
  return (ushort_t)((u + 0x7FFFu + ((u >> 16) & 1u)) >> 16);
}

// ---------------------------------------------------------------------------
// Prep: pack points as (x,y,z,|p|^2); convert W[512][128] -> bf16 Wb[512][128]
// (r9/r10-verified)
// ---------------------------------------------------------------------------
__global__ __launch_bounds__(256) void prep_kernel(
    const float* __restrict__ gpcd, const float* __restrict__ W,
    float4* __restrict__ pts4, ushort_t* __restrict__ Wb)
{
  int tid = blockIdx.x * 256 + threadIdx.x;   // 0..65535
  if (tid < NB * NP) {
    const float* p = gpcd + (size_t)tid * 3;
    float x = p[0], y = p[1], z = p[2];
    float p2 = x * x + y * y + z * z;
    pts4[tid] = make_float4(x, y, z, p2);
  }
  Wb[tid] = f2bf(W[tid]);                     // 512*128 = 65536 elements
}

// ---------------------------------------------------------------------------
// Stage A+B (r10-verified pass 1 + knockout; NEW pass 2):
// Pass 2 no longer inserts inline. Hits against the (monotone-decreasing)
// threshold are compact-written (ballot+popcount) into a per-query LDS
// buffer; the streaming loop carries NO cross-lane dependency, so loads
// pipeline. The <=~20 buffered candidates then run through the verified
// insert_loop once at the end (buffer order = ascending idx; insert is
// order-independent exact anyway). Overflow (count+hits > CAP): wave-uniform
// flush via the same finalize, then r10-verified inline insert for the tile.
// ---------------------------------------------------------------------------
__global__ __launch_bounds__(256) void knn_interp_kernel(
    const float* __restrict__ geometry, const float4* __restrict__ pts4,
    const float* __restrict__ features, ushort_t* __restrict__ Abf)
{
  __shared__ float cdL[4][QW][CAP];
  __shared__ int   ciL[4][QW][CAP];

  const int lane = threadIdx.x & 63;
  const int wb   = threadIdx.x >> 6;    // wave within block
  const int wave = (blockIdx.x << 2) | wb;
  const int q0   = wave * QW;           // QW consecutive queries (same batch)
  const int b    = q0 >> 13;            // q0 / 8192
  const float4* __restrict__ P = pts4 + ((size_t)b << 13);

  float m2x[QW], m2y[QW], m2z[QW], q2[QW];
#pragma unroll
  for (int j = 0; j < QW; ++j) {
    const float* g = geometry + (size_t)(q0 + j) * 3;
    float x = g[0], y = g[1], z = g[2];
    q2[j]  = x * x + y * y + z * z;
    m2x[j] = -2.0f * x; m2y[j] = -2.0f * y; m2z[j] = -2.0f * z;
  }

  // ---- pass 1: per-lane min of shifted d2' (r10-verified) ----
  float lmin[QW];
#pragma unroll
  for (int j = 0; j < QW; ++j) lmin[j] = INFINITY;
#pragma unroll 2
  for (int t = 0; t < NP / 64; ++t) {
    const float4 p = P[(t << 6) | lane];
#pragma unroll
    for (int j = 0; j < QW; ++j)
      lmin[j] = fminf(lmin[j], dist2s(m2x[j], m2y[j], m2z[j], p));
  }

  // ---- tau = 10th-smallest lane-min; th = nextup(tau) (r10-verified) ----
  float th[QW];
#pragma unroll
  for (int j = 0; j < QW; ++j) {
    float lm  = lmin[j];
    float tau = 0.0f;
#pragma unroll
    for (int r = 0; r < KNN; ++r) {
      tau = wmin64f(lm);
      u64 mk = __ballot(lm == tau);
      int w = __builtin_ctzll(mk);
      if (lane == w) lm = INFINITY;
    }
    th[j] = nextupf(tau);               // admits ties at tau
  }

  u64   list[QW];
  float dl[QW];
  int   count[QW];
#pragma unroll
  for (int j = 0; j < QW; ++j) {
    list[j]  = 0xFFFFFFFFFFFFFFFFull;   // maximal key
    dl[j]    = INFINITY;
    count[j] = 0;
  }
  const float qnan = __builtin_nanf("");

  // finalize: run buffered candidates through the verified insert machinery.
  auto finalize = [&](int j) {
    for (int base2 = 0; base2 < count[j]; base2 += 64) {
      const int sidx = base2 + lane;
      float cd2 = qnan;
      int   cid = 0;
      if (sidx < count[j]) { cd2 = cdL[wb][j][sidx]; cid = ciL[wb][j][sidx]; }
      insert_loop(cd2, cid, lane, list[j], dl[j], th[j]);
    }
    count[j] = 0;
  };

  // ---- pass 2: streaming filter + compaction (no loop-carried deps) ----
  for (int t = 0; t < NP / 64; ++t) {
    const float4 p = P[(t << 6) | lane];
    const int  idx = (t << 6) | lane;
#pragma unroll
    for (int j = 0; j < QW; ++j) {
      const float d2 = dist2s(m2x[j], m2y[j], m2z[j], p);
      const bool hit = d2 < th[j];
      const u64 mask = __ballot(hit);
      if (!mask) continue;
      const int pc = __popcll(mask);               // wave-uniform
      if (count[j] + pc > CAP) {                   // rare overflow path
        finalize(j);                               // tightens th[j]
        float d2m = hit ? d2 : qnan;               // re-filter inside insert
        insert_loop(d2m, idx, lane, list[j], dl[j], th[j]);   // r10 inline
      } else {
        if (hit) {
          const int slot = count[j] +
              (int)__popcll(mask & ((1ull << lane) - 1ull));
          cdL[wb][j][slot] = d2;
          ciL[wb][j][slot] = idx;
        }
        count[j] += pc;
      }
    }
  }

  // ---- final selection from buffers ----
#pragma unroll
  for (int j = 0; j < QW; ++j) finalize(j);

  // ---- weights + feature interpolation; bf16 row-major output (r10) ----
  const float* __restrict__ F = features + (size_t)b * NP * NF;
#pragma unroll
  for (int j = 0; j < QW; ++j) {
    float td2 = fmaxf(dl[j] + q2[j], 0.0f);       // back to true d2, clamped
    float w   = 1.0f / (sqrtf(td2) + 1e-8f);      // meaningful on lanes 0..9
    float wsum = 0.0f;
#pragma unroll
    for (int jj = 0; jj < KNN; ++jj) wsum += __shfl(w, jj, 64);

    float a0 = 0.0f, a1 = 0.0f;
#pragma unroll
    for (int jj = 0; jj < KNN; ++jj) {
      float wj = __shfl(w, jj, 64) / wsum;
      int  mi  = (int)(u32)(shfl64(list[j], jj) & 0xffffffffull);
      const float2 f2 = *(const float2*)(F + (size_t)mi * NF + (lane << 1));
      a0 = fmaf(wj, f2.x, a0);
      a1 = fmaf(wj, f2.y, a1);
    }
    unsigned pack = (unsigned)f2bf(a0) | ((unsigned)f2bf(a1) << 16);
    *(unsigned*)(Abf + (size_t)(q0 + j) * NF + (lane << 1)) = pack;
  }
}

// ---------------------------------------------------------------------------
// Stage C (MFMA, r9/r10-verified): out[q][o] = sum_f A[q][f]*Wb[o][f]+bias[o]
// ---------------------------------------------------------------------------
__global__ __launch_bounds__(256) void proj_mfma(
    const ushort_t* __restrict__ Abf, const ushort_t* __restrict__ Wb,
    const float* __restrict__ bias, float* __restrict__ out)
{
  const int lane = threadIdx.x & 63;
  const int w    = threadIdx.x >> 6;        // wave 0..3
  const int mt   = blockIdx.x & 127;        // 128 m-blocks
  const int ot   = blockIdx.x >> 7;         // 8 o-blocks
  const int m0   = (mt << 7) + ((w & 1) << 6);   // wave's 64-row band
  const int o0   = (ot << 6) + ((w >> 1) << 5);  // wave's 32-col band
  const int r    = lane & 15;
  const int kg   = (lane >> 4) << 3;        // k offset 0,8,16,24

  f32x4 acc[4][2];
#pragma unroll
  for (int i = 0; i < 4; ++i)
#pragma unroll
    for (int jn = 0; jn < 2; ++jn) acc[i][jn] = (f32x4)0.0f;

#pragma unroll
  for (int ks = 0; ks < 4; ++ks) {
    const int k0 = (ks << 5) + kg;
    bf16x8 a[4], bb[2];
#pragma unroll
    for (int i = 0; i < 4; ++i)
      a[i] = *(const bf16x8*)(Abf + (size_t)(m0 + (i << 4) + r) * NF + k0);
#pragma unroll
    for (int jn = 0; jn < 2; ++jn)
      bb[jn] = *(const bf16x8*)(Wb + (size_t)(o0 + (jn << 4) + r) * NF + k0);
#pragma unroll
    for (int i = 0; i < 4; ++i)
#pragma unroll
      for (int jn = 0; jn < 2; ++jn)
        acc[i][jn] = __builtin_amdgcn_mfma_f32_16x16x32_bf16(
            a[i], bb[jn], acc[i][jn], 0, 0, 0);
  }

  const int crow = (lane >> 4) << 2;
#pragma unroll
  for (int jn = 0; jn < 2; ++jn) {
    const int oc = o0 + (jn << 4) + r;
    const float bv = bias[oc];
#pragma unroll
    for (int i = 0; i < 4; ++i) {
#pragma unroll
      for (int reg = 0; reg < 4; ++reg) {
        const int qm = m0 + (i << 4) + crow + reg;
        out[(size_t)qm * NOUT + oc] = acc[i][jn][reg] + bv;
      }
    }
  }
}

// ---------------------------------------------------------------------------
extern "C" void kernel_launch(void* const* d_in, const int* in_sizes, int n_in,
                              void* d_out, int out_size, void* d_ws, size_t ws_size,
                              hipStream_t stream) {
  const float* geometry = (const float*)d_in[0];   // [2,8192,3]
  const float* gpcd     = (const float*)d_in[1];   // [2,8192,3]
  const float* features = (const float*)d_in[2];   // [2,8192,128]
  const float* W        = (const float*)d_in[3];   // [512,128]
  const float* bias     = (const float*)d_in[4];   // [512]
  float* out = (float*)d_out;

  // workspace: Abf 4 MiB | pts4 256 KiB | Wb 128 KiB
  char*     ws   = (char*)d_ws;
  ushort_t* Abf  = (ushort_t*)ws;
  float4*   pts4 = (float4*)(ws + (size_t)BNQ * NF * 2);
  ushort_t* Wb   = (ushort_t*)(ws + (size_t)BNQ * NF * 2 + (size_t)NB * NP * 16);

  prep_kernel<<<256, 256, 0, stream>>>(gpcd, W, pts4, Wb);
  knn_interp_kernel<<<BNQ / (QW * 4), 256, 0, stream>>>(geometry, pts4, features, Abf);
  proj_mfma<<<(BNQ / 128) * (NOUT / 64), 256, 0, stream>>>(Abf, Wb, bias, out);
}

// Round 19
// 107.486 us; speedup vs baseline: 1.2653x; 1.0017x over previous
//
#include <hip/hip_runtime.h>
#include <math.h>

#define NQ   8192      // N queries per batch
#define NP   8192      // M points per batch
#define NF   128       // feature dim
#define NOUT 512       // output dim
#define NB   2         // batches
#define KNN  10
#define BNQ  (NB*NQ)   // 16384 total queries
#define QW   2         // queries per wave
#define CAP  64        // candidate buffer slots per query
#define STILES 32      // pass-1 subset tiles (2048 points): tau_S >= true tau

typedef unsigned long long u64;
typedef unsigned int u32;
typedef unsigned short ushort_t;
typedef __attribute__((ext_vector_type(8))) short bf16x8;
typedef __attribute__((ext_vector_type(4))) float f32x4;

__device__ __forceinline__ u64 shfl64(u64 v, int src) {
  unsigned lo = (unsigned)__shfl((int)(unsigned)(v & 0xffffffffull), src, 64);
  unsigned hi = (unsigned)__shfl((int)(unsigned)(v >> 32), src, 64);
  return ((u64)hi << 32) | lo;
}
__device__ __forceinline__ u64 shflup64(u64 v) {
  unsigned lo = (unsigned)__shfl_up((int)(unsigned)(v & 0xffffffffull), 1, 64);
  unsigned hi = (unsigned)__shfl_up((int)(unsigned)(v >> 32), 1, 64);
  return ((u64)hi << 32) | lo;
}

// Shifted distance for SELECTION: d2' = p2 - 2 q.p  (3 fma). True d2 = d2'+q2.
__device__ __forceinline__ float dist2s(float m2x, float m2y, float m2z,
                                        float4 p) {
  return fmaf(m2x, p.x, fmaf(m2y, p.y, fmaf(m2z, p.z, p.w)));
}

// Monotone f32->u32 bit map: mono(a) < mono(b) (unsigned) <=> a < b (float).
__device__ __forceinline__ unsigned fmono(float f) {
  unsigned u = __float_as_uint(f);
  return u ^ ((unsigned)((int)u >> 31) | 0x80000000u);
}
// nextafter(f, +inf) for finite f incl. negatives and -0 (r7-verified).
__device__ __forceinline__ float nextupf(float f) {
  unsigned u = __float_as_uint(f);
  unsigned n = (u & 0x80000000u) ? ((u == 0x80000000u) ? 1u : u - 1u) : u + 1u;
  return __uint_as_float(n);
}

__device__ __forceinline__ float wmin64f(float v) {
#pragma unroll
  for (int off = 1; off < 64; off <<= 1)
    v = fminf(v, __shfl_xor(v, off, 64));
  return v;   // broadcast min across all 64 lanes (r5-verified)
}

// r8-verified order-independent distributed insert (full-exec only).
__device__ __forceinline__ void insert_loop(float d2, int idxv, int lane,
                                            u64& lst, float& dlv, float& th) {
  for (;;) {
    u64 mask = __ballot(d2 < th);
    if (!mask) break;
    int src = __builtin_ctzll(mask);
    float cd = __uint_as_float(
        (unsigned)__builtin_amdgcn_readlane(__float_as_int(d2), src));
    int  ci = __builtin_amdgcn_readlane(idxv, src);
    u64 kk = ((u64)fmono(cd) << 32) | (u32)ci;
    u64   prev  = shflup64(lst);
    float prevd = __shfl(dlv, lane - 1, 64);
    bool mylt = lst < kk;
    bool pins = (lane == 0) || (prev < kk);
    lst = mylt ? lst : (pins ? kk : prev);
    dlv = mylt ? dlv : (pins ? cd : prevd);
    float d9 = __uint_as_float(
        (unsigned)__builtin_amdgcn_readlane(__float_as_int(dlv), 9));
    th = fminf(th, nextupf(d9));
    if (lane == src) d2 = __builtin_nanf("");
  }
}

// round-to-nearest-even f32 -> bf16
__device__ __forceinline__ ushort_t f2bf(float x) {
  unsigned u = __float_as_uint(x);
  return (ushort_t)((u + 0x7FFFu + ((u >> 16) & 1u)) >> 16);
}

// ---------------------------------------------------------------------------
// Prep: pack points as (x,y,z,|p|^2); convert W[512][128] -> bf16 Wb[512][128]
// (r9/r10-verified)
// ---------------------------------------------------------------------------
__global__ __launch_bounds__(256) void prep_kernel(
    const float* __restrict__ gpcd, const float* __restrict__ W,
    float4* __restrict__ pts4, ushort_t* __restrict__ Wb)
{
  int tid = blockIdx.x * 256 + threadIdx.x;   // 0..65535
  if (tid < NB * NP) {
    const float* p = gpcd + (size_t)tid * 3;
    float x = p[0], y = p[1], z = p[2];
    float p2 = x * x + y * y + z * z;
    pts4[tid] = make_float4(x, y, z, p2);
  }
  Wb[tid] = f2bf(W[tid]);                     // 512*128 = 65536 elements
}

// ---------------------------------------------------------------------------
// Stage A+B (r18-verified structure; pass 1 now over a SUBSET):
// Pass 1 scans only the first 2048 points. tau_S = 10th-smallest lane-min of
// the subset >= true 10th-NN distance, so th = nextup(tau_S) is a valid
// (looser) filter: every true top-10 member passes. E[hits] ~= 40 < CAP;
// overflow (rare) uses the r18-verified mid-stream finalize which tightens
// th before continuing. Pass 2 = full filtered scan with LDS compaction
// (no loop-carried cross-lane deps -> loads pipeline). Final selection via
// the r8-verified order-independent insert_loop. Exact top-k + tie-breaks.
// ---------------------------------------------------------------------------
__global__ __launch_bounds__(256) void knn_interp_kernel(
    const float* __restrict__ geometry, const float4* __restrict__ pts4,
    const float* __restrict__ features, ushort_t* __restrict__ Abf)
{
  __shared__ float cdL[4][QW][CAP];
  __shared__ int   ciL[4][QW][CAP];

  const int lane = threadIdx.x & 63;
  const int wb   = threadIdx.x >> 6;    // wave within block
  const int wave = (blockIdx.x << 2) | wb;
  const int q0   = wave * QW;           // QW consecutive queries (same batch)
  const int b    = q0 >> 13;            // q0 / 8192
  const float4* __restrict__ P = pts4 + ((size_t)b << 13);

  float m2x[QW], m2y[QW], m2z[QW], q2[QW];
#pragma unroll
  for (int j = 0; j < QW; ++j) {
    const float* g = geometry + (size_t)(q0 + j) * 3;
    float x = g[0], y = g[1], z = g[2];
    q2[j]  = x * x + y * y + z * z;
    m2x[j] = -2.0f * x; m2y[j] = -2.0f * y; m2z[j] = -2.0f * z;
  }

  // ---- pass 1 (SUBSET): per-lane min of shifted d2' over 2048 points ----
  float lmin[QW];
#pragma unroll
  for (int j = 0; j < QW; ++j) lmin[j] = INFINITY;
#pragma unroll 2
  for (int t = 0; t < STILES; ++t) {
    const float4 p = P[(t << 6) | lane];
#pragma unroll
    for (int j = 0; j < QW; ++j)
      lmin[j] = fminf(lmin[j], dist2s(m2x[j], m2y[j], m2z[j], p));
  }

  // ---- tau_S = 10th-smallest lane-min of subset; th = nextup(tau_S) ----
  float th[QW];
#pragma unroll
  for (int j = 0; j < QW; ++j) {
    float lm  = lmin[j];
    float tau = 0.0f;
#pragma unroll
    for (int r = 0; r < KNN; ++r) {
      tau = wmin64f(lm);
      u64 mk = __ballot(lm == tau);
      int w = __builtin_ctzll(mk);
      if (lane == w) lm = INFINITY;
    }
    th[j] = nextupf(tau);               // admits ties at tau
  }

  u64   list[QW];
  float dl[QW];
  int   count[QW];
#pragma unroll
  for (int j = 0; j < QW; ++j) {
    list[j]  = 0xFFFFFFFFFFFFFFFFull;   // maximal key
    dl[j]    = INFINITY;
    count[j] = 0;
  }
  const float qnan = __builtin_nanf("");

  // finalize: run buffered candidates through the verified insert machinery.
  auto finalize = [&](int j) {
    for (int base2 = 0; base2 < count[j]; base2 += 64) {
      const int sidx = base2 + lane;
      float cd2 = qnan;
      int   cid = 0;
      if (sidx < count[j]) { cd2 = cdL[wb][j][sidx]; cid = ciL[wb][j][sidx]; }
      insert_loop(cd2, cid, lane, list[j], dl[j], th[j]);
    }
    count[j] = 0;
  };

  // ---- pass 2: streaming filter + compaction (no loop-carried deps) ----
  for (int t = 0; t < NP / 64; ++t) {
    const float4 p = P[(t << 6) | lane];
    const int  idx = (t << 6) | lane;
#pragma unroll
    for (int j = 0; j < QW; ++j) {
      const float d2 = dist2s(m2x[j], m2y[j], m2z[j], p);
      const bool hit = d2 < th[j];
      const u64 mask = __ballot(hit);
      if (!mask) continue;
      const int pc = __popcll(mask);               // wave-uniform
      if (count[j] + pc > CAP) {                   // overflow path
        finalize(j);                               // tightens th[j]
        float d2m = hit ? d2 : qnan;               // re-filter inside insert
        insert_loop(d2m, idx, lane, list[j], dl[j], th[j]);   // r10 inline
      } else {
        if (hit) {
          const int slot = count[j] +
              (int)__popcll(mask & ((1ull << lane) - 1ull));
          cdL[wb][j][slot] = d2;
          ciL[wb][j][slot] = idx;
        }
        count[j] += pc;
      }
    }
  }

  // ---- final selection from buffers ----
#pragma unroll
  for (int j = 0; j < QW; ++j) finalize(j);

  // ---- weights + feature interpolation; bf16 row-major output (r10) ----
  const float* __restrict__ F = features + (size_t)b * NP * NF;
#pragma unroll
  for (int j = 0; j < QW; ++j) {
    float td2 = fmaxf(dl[j] + q2[j], 0.0f);       // back to true d2, clamped
    float w   = 1.0f / (sqrtf(td2) + 1e-8f);      // meaningful on lanes 0..9
    float wsum = 0.0f;
#pragma unroll
    for (int jj = 0; jj < KNN; ++jj) wsum += __shfl(w, jj, 64);

    float a0 = 0.0f, a1 = 0.0f;
#pragma unroll
    for (int jj = 0; jj < KNN; ++jj) {
      float wj = __shfl(w, jj, 64) / wsum;
      int  mi  = (int)(u32)(shfl64(list[j], jj) & 0xffffffffull);
      const float2 f2 = *(const float2*)(F + (size_t)mi * NF + (lane << 1));
      a0 = fmaf(wj, f2.x, a0);
      a1 = fmaf(wj, f2.y, a1);
    }
    unsigned pack = (unsigned)f2bf(a0) | ((unsigned)f2bf(a1) << 16);
    *(unsigned*)(Abf + (size_t)(q0 + j) * NF + (lane << 1)) = pack;
  }
}

// ---------------------------------------------------------------------------
// Stage C (MFMA, r9/r10-verified): out[q][o] = sum_f A[q][f]*Wb[o][f]+bias[o]
// ---------------------------------------------------------------------------
__global__ __launch_bounds__(256) void proj_mfma(
    const ushort_t* __restrict__ Abf, const ushort_t* __restrict__ Wb,
    const float* __restrict__ bias, float* __restrict__ out)
{
  const int lane = threadIdx.x & 63;
  const int w    = threadIdx.x >> 6;        // wave 0..3
  const int mt   = blockIdx.x & 127;        // 128 m-blocks
  const int ot   = blockIdx.x >> 7;         // 8 o-blocks
  const int m0   = (mt << 7) + ((w & 1) << 6);   // wave's 64-row band
  const int o0   = (ot << 6) + ((w >> 1) << 5);  // wave's 32-col band
  const int r    = lane & 15;
  const int kg   = (lane >> 4) << 3;        // k offset 0,8,16,24

  f32x4 acc[4][2];
#pragma unroll
  for (int i = 0; i < 4; ++i)
#pragma unroll
    for (int jn = 0; jn < 2; ++jn) acc[i][jn] = (f32x4)0.0f;

#pragma unroll
  for (int ks = 0; ks < 4; ++ks) {
    const int k0 = (ks << 5) + kg;
    bf16x8 a[4], bb[2];
#pragma unroll
    for (int i = 0; i < 4; ++i)
      a[i] = *(const bf16x8*)(Abf + (size_t)(m0 + (i << 4) + r) * NF + k0);
#pragma unroll
    for (int jn = 0; jn < 2; ++jn)
      bb[jn] = *(const bf16x8*)(Wb + (size_t)(o0 + (jn << 4) + r) * NF + k0);
#pragma unroll
    for (int i = 0; i < 4; ++i)
#pragma unroll
      for (int jn = 0; jn < 2; ++jn)
        acc[i][jn] = __builtin_amdgcn_mfma_f32_16x16x32_bf16(
            a[i], bb[jn], acc[i][jn], 0, 0, 0);
  }

  const int crow = (lane >> 4) << 2;
#pragma unroll
  for (int jn = 0; jn < 2; ++jn) {
    const int oc = o0 + (jn << 4) + r;
    const float bv = bias[oc];
#pragma unroll
    for (int i = 0; i < 4; ++i) {
#pragma unroll
      for (int reg = 0; reg < 4; ++reg) {
        const int qm = m0 + (i << 4) + crow + reg;
        out[(size_t)qm * NOUT + oc] = acc[i][jn][reg] + bv;
      }
    }
  }
}

// ---------------------------------------------------------------------------
extern "C" void kernel_launch(void* const* d_in, const int* in_sizes, int n_in,
                              void* d_out, int out_size, void* d_ws, size_t ws_size,
                              hipStream_t stream) {
  const float* geometry = (const float*)d_in[0];   // [2,8192,3]
  const float* gpcd     = (const float*)d_in[1];   // [2,8192,3]
  const float* features = (const float*)d_in[2];   // [2,8192,128]
  const float* W        = (const float*)d_in[3];   // [512,128]
  const float* bias     = (const float*)d_in[4];   // [512]
  float* out = (float*)d_out;

  // workspace: Abf 4 MiB | pts4 256 KiB | Wb 128 KiB
  char*     ws   = (char*)d_ws;
  ushort_t* Abf  = (ushort_t*)ws;
  float4*   pts4 = (float4*)(ws + (size_t)BNQ * NF * 2);
  ushort_t* Wb   = (ushort_t*)(ws + (size_t)BNQ * NF * 2 + (size_t)NB * NP * 16);

  prep_kernel<<<256, 256, 0, stream>>>(gpcd, W, pts4, Wb);
  knn_interp_kernel<<<BNQ / (QW * 4), 256, 0, stream>>>(geometry, pts4, features, Abf);
  proj_mfma<<<(BNQ / 128) * (NOUT / 64), 256, 0, stream>>>(Abf, Wb, bias, out);
}